// Round 8
// baseline (752.370 us; speedup 1.0000x reference)
//
#include <hip/hip_runtime.h>
#include <math.h>

// ---------------------------------------------------------------------------
// Encoder_75557064671564 — MFMA bf16 conv stack, NHWC intermediates.
//
// ROUND-8: k_cmfma v2 (was 5x107us, VALUBusy 28% > MfmaUtil 21%, occ 21%):
//   - single staging phase for all CIN (8/12 kb in LDS), 1 barrier pair
//   - pixel-major staging (1 index-decode per px, 8x16B loads per 128B line)
//   - v_cvt_pk_bf16_f32 asm for all f32->bf16 packing (same RNE as manual)
//   - __launch_bounds__(256,3): 3 blocks/CU for MODE0
// lp chain: complex-rotation recurrence (round-7, verified).
// Workspace: 134,978,432 B (~128.7 MiB); LP scratch aliases XB.
// ---------------------------------------------------------------------------

#define NPX 65536
typedef unsigned short u16;
typedef __bf16 bfrag_t __attribute__((ext_vector_type(8)));
typedef float f32x4 __attribute__((ext_vector_type(4)));

__constant__ int WM_R_[30] = {124, 125,125,125,125,125, 126,126,126,126,126,126,126,
                              127,127,127,127,127,127,127,
                              128,128,128,128,128,128,128,128,128, 129};
__constant__ int WM_C_[30] = {128, 126,127,128,129,130, 125,126,127,128,129,130,131,
                              125,126,127,128,129,130,131,
                              124,125,126,127,128,129,130,131,132, 125};

__device__ __forceinline__ float bfu2f(unsigned int bits) {
    return __uint_as_float(bits << 16);
}
__device__ __forceinline__ u16 f2bu(float f) {
    unsigned int u = __float_as_uint(f);
    u += 0x7fffu + ((u >> 16) & 1u);
    return (u16)(u >> 16);
}
// RNE pack of 2 floats -> 2 bf16 in one instruction (identical rounding to f2bu)
__device__ __forceinline__ unsigned cvt_pk(float lo, float hi) {
    unsigned r;
    asm("v_cvt_pk_bf16_f32 %0, %1, %2" : "=v"(r) : "v"(lo), "v"(hi));
    return r;
}

// ---------------- tables ----------------
__global__ void k_tables(float* __restrict__ tw, float* __restrict__ d2t,
                         double* __restrict__ twd64) {
    int idx = blockIdx.x * 256 + threadIdx.x;
    if (idx < 256) {
        double ang = -2.0 * M_PI * (double)idx / 256.0;
        tw[idx]       = (float)cos(ang);
        tw[256 + idx] = (float)sin(ang);
        twd64[idx]       = cos(ang);
        twd64[256 + idx] = sin(ang);
    }
    int q = idx - 256;
    if (q >= 0 && q < 256 * 101) {
        int d = q / 101, kxi = q - d * 101;
        int vx = (kxi <= 50) ? kxi : kxi - 101;
        int r2 = 2500 - vx * vx;
        int L = 0;
        while ((L + 1) * (L + 1) <= r2) L++;
        double s = 1.0;
        for (int v = 1; v <= L; v++) s += 2.0 * cos(2.0 * M_PI * (double)(v * d) / 256.0);
        d2t[kxi * 256 + d] = (float)(s / 256.0);
    }
}

// ---------------- low-pass chain (fp64, rotation recurrence) ----------------
__global__ __launch_bounds__(256) void k_lp1(const float* __restrict__ img,
        const double* __restrict__ twd64, float* __restrict__ Y) {
    __shared__ double rowd[4][256];
    int y0 = blockIdx.x * 4, ch = blockIdx.y, tid = threadIdx.x;
#pragma unroll
    for (int r = 0; r < 4; r++)
        rowd[r][tid] = (double)img[ch * NPX + (y0 + r) * 256 + tid];
    __syncthreads();
    int kxi = tid & 127, rg = tid >> 7;
    if (kxi >= 101) return;
    int kx = (kxi <= 50) ? kxi : kxi + 155;
    double cr = twd64[kx], ci = twd64[256 + kx];   // step e^{-2pi i kx/256}
    double wr = 1.0, wi = 0.0;
    double a0r = 0, a0i = 0, a1r = 0, a1i = 0;
    const double* r0 = rowd[2 * rg];
    const double* r1 = rowd[2 * rg + 1];
    for (int x = 0; x < 256; x++) {
        double v0 = r0[x], v1 = r1[x];
        a0r += v0 * wr; a0i += v0 * wi;
        a1r += v1 * wr; a1i += v1 * wi;
        double t = wr * cr - wi * ci;
        wi = wr * ci + wi * cr;
        wr = t;
    }
    int y = y0 + 2 * rg;
    int o = ((kxi * 24 + ch) * 256 + y) * 2;
    Y[o]     = (float)a0r; Y[o + 1] = (float)a0i;
    Y[o + 2] = (float)a1r; Y[o + 3] = (float)a1i;
}

__global__ __launch_bounds__(256) void k_lp2(const float* __restrict__ Y,
        const float* __restrict__ d2t, float* __restrict__ W) {
    __shared__ double Ys[4][256][2];   // 16 KB
    __shared__ double Dc[256];         // 2 KB
    int kxi = blockIdx.x, chg = blockIdx.y, tid = threadIdx.x;
    const float* src = Y + (size_t)(kxi * 24 + chg * 4) * 512;
    double* ysf = (double*)Ys;
    for (int i = tid; i < 2048; i += 256) ysf[i] = (double)src[i];
    Dc[tid] = (double)d2t[kxi * 256 + tid];
    __syncthreads();
    int cs = tid >> 6, y4 = tid & 63;
    double wr[4] = {0, 0, 0, 0}, wi[4] = {0, 0, 0, 0};
    for (int yp = 0; yp < 256; yp++) {
        double yr = Ys[cs][yp][0], yi = Ys[cs][yp][1];
        double D0 = Dc[(y4 - yp) & 255];
        double D1 = Dc[(y4 + 64 - yp) & 255];
        double D2 = Dc[(y4 + 128 - yp) & 255];
        double D3 = Dc[(y4 + 192 - yp) & 255];
        wr[0] += D0 * yr; wi[0] += D0 * yi;
        wr[1] += D1 * yr; wi[1] += D1 * yi;
        wr[2] += D2 * yr; wi[2] += D2 * yi;
        wr[3] += D3 * yr; wi[3] += D3 * yi;
    }
    int ch = chg * 4 + cs;
#pragma unroll
    for (int k = 0; k < 4; k++) {
        int y = y4 + 64 * k;
        int o = ((ch * 256 + y) * 101 + kxi) * 2;
        W[o] = (float)wr[k]; W[o + 1] = (float)wi[k];
    }
}

__global__ __launch_bounds__(256) void k_lp3(const float* __restrict__ W,
        const double* __restrict__ twd64, float* __restrict__ lp) {
    __shared__ double wsr[101], wsi[101];
    int y = blockIdx.x, ch = blockIdx.y, x = threadIdx.x;
    if (x < 101) {
        int kxi = (x < 50) ? (x + 51) : (x - 50);   // j=x -> kx=j-50
        wsr[x] = (double)W[((ch * 256 + y) * 101 + kxi) * 2];
        wsi[x] = (double)W[((ch * 256 + y) * 101 + kxi) * 2 + 1];
    }
    __syncthreads();
    int t0 = (50 * x) & 255;
    double wr = twd64[t0], wi = -twd64[256 + t0];
    double cr = twd64[x], ci = twd64[256 + x];
    double acc = 0.0;
    for (int j = 0; j < 101; j++) {
        acc += wsr[j] * wr + wsi[j] * wi;
        double t = wr * cr - wi * ci;
        wi = wr * ci + wi * cr;
        wr = t;
    }
    acc *= (1.0 / 256.0);
    acc = floor(fmin(fmax(acc, 0.0), 255.0)) / 255.0;
    lp[ch * NPX + y * 256 + x] = (float)acc;
}

// ---------------- conv1: CIN=3, fp32 VALU, NHWC bf16 out ----------------
__global__ __launch_bounds__(256, 2) void k_conv1(
    const float* __restrict__ lp, const float* __restrict__ w0,
    u16* __restrict__ out) {
    __shared__ float wl[3][9][64];
    __shared__ float al[3][18][18];
    int tid = threadIdx.x;
    int b = blockIdx.z, r0 = blockIdx.y * 16, c0 = blockIdx.x * 16;
    int ocg = tid >> 5, pxg = tid & 31;
    int row = pxg >> 1, chof = (pxg & 1) * 8;
    int oc0 = ocg * 8;
    float acc[8][8];
#pragma unroll
    for (int o = 0; o < 8; o++)
#pragma unroll
        for (int p = 0; p < 8; p++) acc[o][p] = 0.f;
    for (int idx = tid; idx < 1728; idx += 256) {
        int ic = idx / 576, rem = idx - ic * 576;
        int tap = rem >> 6, oc = rem & 63;
        wl[ic][tap][oc] = w0[(oc * 3 + ic) * 9 + tap];
    }
    for (int idx = tid; idx < 972; idx += 256) {
        int ic = idx / 324, rem = idx - ic * 324;
        int ly = rem / 18, lx = rem - ly * 18;
        int gy = r0 - 1 + ly, gx = c0 - 1 + lx;
        float v = 0.f;
        if ((unsigned)gy < 256u && (unsigned)gx < 256u)
            v = lp[(b * 3 + ic) * NPX + gy * 256 + gx];
        al[ic][ly][lx] = v;
    }
    __syncthreads();
    for (int ic = 0; ic < 3; ic++) {
        float areg[3][10];
#pragma unroll
        for (int di = 0; di < 3; di++)
#pragma unroll
            for (int xx = 0; xx < 10; xx++) areg[di][xx] = al[ic][row + di][chof + xx];
#pragma unroll
        for (int tap = 0; tap < 9; tap++) {
            const int di = tap / 3, dj = tap % 3;
            float wv[8];
#pragma unroll
            for (int o = 0; o < 8; o++) wv[o] = wl[ic][tap][oc0 + o];
#pragma unroll
            for (int o = 0; o < 8; o++)
#pragma unroll
                for (int p = 0; p < 8; p++)
                    acc[o][p] = fmaf(wv[o], areg[di][dj + p], acc[o][p]);
        }
    }
#pragma unroll
    for (int p = 0; p < 8; p++) {
        unsigned wd[4];
#pragma unroll
        for (int q = 0; q < 4; q++)
            wd[q] = cvt_pk(acc[2 * q][p], acc[2 * q + 1][p]);
        size_t addr = ((size_t)((b * 256 + r0 + row) * 256 + c0 + chof + p)) * 64 + oc0;
        uint4 vv; vv.x = wd[0]; vv.y = wd[1]; vv.z = wd[2]; vv.w = wd[3];
        *reinterpret_cast<uint4*>(out + addr) = vv;
    }
}

// ---------------- weight packing ----------------
__global__ void k_wprep(const float* __restrict__ wsv, u16* __restrict__ wp) {
    int bid = blockIdx.x;                  // 216 = 3 convs * 72
    int conv = bid / 72, fg = bid % 72;
    int icc = fg / 36, t2 = fg % 36, tap = t2 / 4, ocb = t2 % 4;
    int l = threadIdx.x;                   // 64
    int oc = ocb * 16 + (l & 15);
    unsigned wd[4];
#pragma unroll
    for (int q = 0; q < 4; q++) {
        int ic0 = icc * 32 + (l >> 4) * 8 + 2 * q;
        float v0 = wsv[conv * 36864 + (oc * 64 + ic0) * 9 + tap];
        float v1 = wsv[conv * 36864 + (oc * 64 + ic0 + 1) * 9 + tap];
        wd[q] = (unsigned)f2bu(v0) | ((unsigned)f2bu(v1) << 16);
    }
    uint4 vv; vv.x = wd[0]; vv.y = wd[1]; vv.z = wd[2]; vv.w = wd[3];
    reinterpret_cast<uint4*>(wp)[conv * 4608 + fg * 64 + l] = vv;
}

__global__ void k_wprep5(const float* __restrict__ acw, u16* __restrict__ wp5) {
    int fg = blockIdx.x;                   // 108
    int icc = fg / 36, t2 = fg % 36, tap = t2 / 4, ocb = t2 % 4;
    int l = threadIdx.x;
    int oc = ocb * 16 + (l & 15);
    unsigned wd[4];
#pragma unroll
    for (int q = 0; q < 4; q++) {
        unsigned out2 = 0;
#pragma unroll
        for (int h = 0; h < 2; h++) {
            int icp = icc * 32 + (l >> 4) * 8 + 2 * q + h;
            float v = 0.f;
            if (icp < 67) v = acw[(oc * 97 + 30 + icp) * 9 + tap];
            out2 |= ((unsigned)f2bu(v)) << (16 * h);
        }
        wd[q] = out2;
    }
    uint4 vv; vv.x = wd[0]; vv.y = wd[1]; vv.z = wd[2]; vv.w = wd[3];
    reinterpret_cast<uint4*>(wp5)[fg * 64 + l] = vv;
}

__global__ void k_wsum(const float* __restrict__ acw, float* __restrict__ wsum) {
    for (int e = threadIdx.x; e < 17280; e += 256) {
        int oc = e / 270, r2 = e % 270, ic = r2 / 9, cls = r2 % 9;
        int cy = cls / 3, cx = cls % 3;
        int dil = (cy == 0) ? 1 : 0, dih = (cy == 2) ? 1 : 2;
        int djl = (cx == 0) ? 1 : 0, djh = (cx == 2) ? 1 : 2;
        float s = 0.f;
        for (int di = dil; di <= dih; di++)
            for (int dj = djl; dj <= djh; dj++)
                s += acw[(oc * 97 + ic) * 9 + di * 3 + dj];
        wsum[e] = s;
    }
}

__global__ void k_msgM(const float* __restrict__ msg, const float* __restrict__ wsum,
                       float* __restrict__ M) {
    int b = blockIdx.x;
    for (int t = threadIdx.x; t < 576; t += 256) {
        int oc = t / 9, cls = t % 9;
        float s = 0.f;
        for (int ic = 0; ic < 30; ic++)
            s += msg[b * 30 + ic] * wsum[oc * 270 + ic * 9 + cls];
        M[b * 576 + t] = s;
    }
}

// ---------------- MFMA conv3x3 (convs 2-5), v2 ----------------
// Single staging phase for all CIN; pixel-major staging; cvt_pk packing.
// MODE 0: CIN=64 (8 kb). MODE 1: conv5, 12 kb (8 enc + 1 img + 3 zero).
template <int MODE>
__global__ __launch_bounds__(256, 3) void k_cmfma(
    const u16* __restrict__ src, const u16* __restrict__ wp,
    const float* __restrict__ st, const float* __restrict__ img,
    const float* __restrict__ dlt, const float* __restrict__ tw,
    const float* __restrict__ Mterm, u16* __restrict__ out) {
    const int NKB = (MODE == 0) ? 8 : 12;
    __shared__ __align__(16) u16 ain[NKB * 324 * 8];   // [kb][px][j]
    __shared__ float sst[128];
    __shared__ float twl[(MODE == 1) ? 512 : 1];
    __shared__ float dl[(MODE == 1) ? 60 : 1];
    __shared__ float Ml[(MODE == 1) ? 576 : 1];

    int tid = threadIdx.x;
    int wv = tid >> 6, l = tid & 63;
    int b = blockIdx.z, y0 = blockIdx.y * 16, x0 = blockIdx.x * 16;

    if (tid < 128) sst[tid] = st[tid];
    if (MODE == 1) {
        twl[tid] = tw[tid]; twl[tid + 256] = tw[tid + 256];
        if (tid < 60) dl[tid] = dlt[b * 60 + tid];
        for (int i = tid; i < 576; i += 256) Ml[i] = Mterm[b * 576 + i];
    }
    __syncthreads();

    // ---- staging: one pass over all pixels, all kb ----
    for (int px = tid; px < 324; px += 256) {
        int ly = px / 18, lx = px - ly * 18;
        int gy = y0 - 1 + ly, gx = x0 - 1 + lx;
        bool inb = ((unsigned)gy < 256u) && ((unsigned)gx < 256u);
        uint4* dst = reinterpret_cast<uint4*>(ain) + px;
        const uint4* gp = nullptr;
        if (inb) gp = reinterpret_cast<const uint4*>(
            src + ((size_t)((b * 256 + gy) * 256 + gx)) * 64);
        float corr = 0.f;
        if (MODE == 1) {
            if (inb) {
#pragma unroll
                for (int p = 0; p < 30; p++) {
                    int t = (WM_R_[p] * gy + WM_C_[p] * gx) & 255;
                    corr += dl[2 * p] * twl[t] + dl[2 * p + 1] * twl[256 + t];
                }
                corr *= (1.0f / 65536.0f);
            }
        }
#pragma unroll
        for (int kb = 0; kb < 8; kb++) {
            uint4 pk; pk.x = 0; pk.y = 0; pk.z = 0; pk.w = 0;
            if (inb) {
                uint4 u = gp[kb];
                int cb = kb * 8;
                float f0 = fmaxf(bfu2f(u.x & 0xffffu) * sst[2 * cb + 0]  + sst[2 * cb + 1],  0.f);
                float f1 = fmaxf(bfu2f(u.x >> 16)     * sst[2 * cb + 2]  + sst[2 * cb + 3],  0.f);
                float f2 = fmaxf(bfu2f(u.y & 0xffffu) * sst[2 * cb + 4]  + sst[2 * cb + 5],  0.f);
                float f3 = fmaxf(bfu2f(u.y >> 16)     * sst[2 * cb + 6]  + sst[2 * cb + 7],  0.f);
                float f4 = fmaxf(bfu2f(u.z & 0xffffu) * sst[2 * cb + 8]  + sst[2 * cb + 9],  0.f);
                float f5 = fmaxf(bfu2f(u.z >> 16)     * sst[2 * cb + 10] + sst[2 * cb + 11], 0.f);
                float f6 = fmaxf(bfu2f(u.w & 0xffffu) * sst[2 * cb + 12] + sst[2 * cb + 13], 0.f);
                float f7 = fmaxf(bfu2f(u.w >> 16)     * sst[2 * cb + 14] + sst[2 * cb + 15], 0.f);
                if (MODE == 1 && kb == 0) f0 += corr;
                pk.x = cvt_pk(f0, f1); pk.y = cvt_pk(f2, f3);
                pk.z = cvt_pk(f4, f5); pk.w = cvt_pk(f6, f7);
            }
            dst[kb * 324] = pk;
        }
        if (MODE == 1) {
            uint4 p8; p8.x = 0; p8.y = 0; p8.z = 0; p8.w = 0;
            if (inb) {
                float v0 = img[(b * 3 + 0) * NPX + gy * 256 + gx];
                float v1 = img[(b * 3 + 1) * NPX + gy * 256 + gx];
                float v2 = img[(b * 3 + 2) * NPX + gy * 256 + gx];
                p8.x = cvt_pk(v0, v1);
                p8.y = cvt_pk(v2, 0.f);
            }
            dst[8 * 324] = p8;
            uint4 z; z.x = 0; z.y = 0; z.z = 0; z.w = 0;
            dst[9 * 324] = z; dst[10 * 324] = z; dst[11 * 324] = z;
        }
    }
    __syncthreads();

    // ---- MFMA phase ----
    f32x4 acc[4][4];
#pragma unroll
    for (int nt = 0; nt < 4; nt++)
#pragma unroll
        for (int ob = 0; ob < 4; ob++) acc[nt][ob] = (f32x4)(0.f);

    const uint4* wq = reinterpret_cast<const uint4*>(wp);
    const uint4* ap = reinterpret_cast<const uint4*>(ain);
    const int bl = (l >> 4) * 324 + (l & 15);
    const int wv4 = wv * 4;
    const int NIT = (NKB / 4) * 9;

    uint4 a0 = wq[l], a1 = wq[64 + l], a2 = wq[128 + l], a3 = wq[192 + l];
#pragma unroll 1
    for (int it = 0; it < NIT; it++) {
        uint4 n0, n1, n2, n3;
        if (it + 1 < NIT) {
            const uint4* q = wq + (it + 1) * 256 + l;
            n0 = q[0]; n1 = q[64]; n2 = q[128]; n3 = q[192];
        }
        int icc = it / 9, tap = it - icc * 9;
        int di = tap / 3, dj = tap - di * 3;
        int abase = icc * 4 * 324 + bl + dj;
#pragma unroll
        for (int nt = 0; nt < 4; nt++) {
            uint4 braw = ap[abase + (wv4 + nt + di) * 18];
            bfrag_t bf = __builtin_bit_cast(bfrag_t, braw);
            acc[nt][0] = __builtin_amdgcn_mfma_f32_16x16x32_bf16(
                __builtin_bit_cast(bfrag_t, a0), bf, acc[nt][0], 0, 0, 0);
            acc[nt][1] = __builtin_amdgcn_mfma_f32_16x16x32_bf16(
                __builtin_bit_cast(bfrag_t, a1), bf, acc[nt][1], 0, 0, 0);
            acc[nt][2] = __builtin_amdgcn_mfma_f32_16x16x32_bf16(
                __builtin_bit_cast(bfrag_t, a2), bf, acc[nt][2], 0, 0, 0);
            acc[nt][3] = __builtin_amdgcn_mfma_f32_16x16x32_bf16(
                __builtin_bit_cast(bfrag_t, a3), bf, acc[nt][3], 0, 0, 0);
        }
        a0 = n0; a1 = n1; a2 = n2; a3 = n3;
    }

    // ---- epilogue ----
    int x = x0 + (l & 15);
    int ocq = (l >> 4) * 4;
    int clsx = (x == 0) ? 0 : ((x == 255) ? 2 : 1);
#pragma unroll
    for (int nt = 0; nt < 4; nt++) {
        int y = y0 + wv4 + nt;
#pragma unroll
        for (int ob = 0; ob < 4; ob++) {
            int oc = ob * 16 + ocq;
            float v0 = acc[nt][ob][0], v1 = acc[nt][ob][1];
            float v2 = acc[nt][ob][2], v3 = acc[nt][ob][3];
            if (MODE == 1) {
                int cls = ((y == 0) ? 0 : ((y == 255) ? 6 : 3)) + clsx;
                v0 += Ml[(oc + 0) * 9 + cls];
                v1 += Ml[(oc + 1) * 9 + cls];
                v2 += Ml[(oc + 2) * 9 + cls];
                v3 += Ml[(oc + 3) * 9 + cls];
            }
            uint2 pk;
            pk.x = cvt_pk(v0, v1);
            pk.y = cvt_pk(v2, v3);
            size_t addr = ((size_t)((b * 256 + y) * 256 + x)) * 64 + oc;
            *reinterpret_cast<uint2*>(out + addr) = pk;
        }
    }
}

// ---------------- BN stats over NHWC raw bf16 ----------------
__global__ void k_stats(const u16* __restrict__ y, float* __restrict__ part) {
    __shared__ float red[2048];
    int blk = blockIdx.x, tid = threadIdx.x;
    int j = tid & 7, g = tid >> 3;
    float s1[8], s2[8];
#pragma unroll
    for (int k = 0; k < 8; k++) { s1[k] = 0.f; s2[k] = 0.f; }
    for (int it = 0; it < 64; it++) {
        int px = blk * 2048 + it * 32 + g;
        uint4 u = *reinterpret_cast<const uint4*>(y + (size_t)px * 64 + j * 8);
        unsigned wd[4] = {u.x, u.y, u.z, u.w};
#pragma unroll
        for (int q = 0; q < 4; q++) {
            float v0 = bfu2f(wd[q] & 0xffffu), v1 = bfu2f(wd[q] >> 16);
            s1[2 * q] += v0; s2[2 * q] += v0 * v0;
            s1[2 * q + 1] += v1; s2[2 * q + 1] += v1 * v1;
        }
    }
#pragma unroll
    for (int k = 0; k < 8; k++) red[tid * 8 + k] = s1[k];
    __syncthreads();
    if (tid < 64) {
        float a = 0.f;
        for (int gg = 0; gg < 32; gg++) a += red[gg * 64 + tid];
        part[blk * 128 + tid * 2] = a;
    }
    __syncthreads();
#pragma unroll
    for (int k = 0; k < 8; k++) red[tid * 8 + k] = s2[k];
    __syncthreads();
    if (tid < 64) {
        float a = 0.f;
        for (int gg = 0; gg < 32; gg++) a += red[gg * 64 + tid];
        part[blk * 128 + tid * 2 + 1] = a;
    }
}

__global__ void k_finalize(const float* __restrict__ part, const float* __restrict__ g,
                           const float* __restrict__ be, float* __restrict__ st) {
    __shared__ double d1[256], d2[256];
    int tid = threadIdx.x;
    int c = tid >> 2, q = tid & 3;
    double S1 = 0.0, S2 = 0.0;
    for (int k = 0; k < 64; k++) {
        int blk = q * 64 + k;
        S1 += (double)part[blk * 128 + c * 2];
        S2 += (double)part[blk * 128 + c * 2 + 1];
    }
    d1[tid] = S1; d2[tid] = S2;
    __syncthreads();
    if (tid < 64) {
        double T1 = 0.0, T2 = 0.0;
        for (int qq = 0; qq < 4; qq++) { T1 += d1[tid * 4 + qq]; T2 += d2[tid * 4 + qq]; }
        const double Nn = 524288.0;
        double mean = T1 / Nn;
        double var = T2 / Nn - mean * mean;
        float s = (float)((double)g[tid] / sqrt(var + 1e-5));
        float t = (float)((double)be[tid] - mean * (double)s);
        st[tid * 2] = s; st[tid * 2 + 1] = t;
    }
}

// ---------------- watermark coefficient passes ----------------
__global__ void k_wmG(const u16* __restrict__ y4, const float* __restrict__ st,
                      const float* __restrict__ tw, float* __restrict__ G) {
    __shared__ float twl[512];
    __shared__ float red[256][12];
    int b = blockIdx.x, xg = blockIdx.y, tid = threadIdx.x;
    twl[tid] = tw[tid]; twl[tid + 256] = tw[tid + 256];
    __syncthreads();
    int xs = tid & 31, x = xg * 32 + xs, yg = tid >> 5;
    float s0 = st[0], t0 = st[1];
    float gr[6], gi[6];
#pragma unroll
    for (int r = 0; r < 6; r++) { gr[r] = 0.f; gi[r] = 0.f; }
    for (int yy = 0; yy < 32; yy++) {
        int y = yg * 32 + yy;
        float v = fmaxf(bfu2f((unsigned)y4[((size_t)((b * 256 + y) * 256 + x)) * 64]) * s0 + t0, 0.f);
#pragma unroll
        for (int r = 0; r < 6; r++) {
            int t = ((124 + r) * y) & 255;
            gr[r] += v * twl[t];
            gi[r] += v * twl[256 + t];
        }
    }
#pragma unroll
    for (int r = 0; r < 6; r++) { red[tid][2 * r] = gr[r]; red[tid][2 * r + 1] = gi[r]; }
    __syncthreads();
    for (int e = tid; e < 384; e += 256) {
        int xs2 = e & 31, c = e >> 5;
        float s = 0.f;
        for (int g = 0; g < 8; g++) s += red[g * 32 + xs2][c];
        int r = c >> 1, ri = c & 1;
        G[((b * 6 + r) * 256 + (xg * 32 + xs2)) * 2 + ri] = s;
    }
}

__global__ void k_wmC(const float* __restrict__ G, const float* __restrict__ msg,
                      const float* __restrict__ tw, float* __restrict__ dlt) {
    __shared__ float twl[512];
    __shared__ float fr[256], fi[256];
    int b = blockIdx.x, tid = threadIdx.x;
    twl[tid] = tw[tid]; twl[tid + 256] = tw[tid + 256];
    __syncthreads();
    int p = tid >> 3, part = tid & 7;
    float Fr = 0.f, Fi = 0.f;
    if (p < 30) {
        int rp = WM_R_[p] - 124, c = WM_C_[p];
        for (int xx = part * 32; xx < part * 32 + 32; xx++) {
            float gr = G[((b * 6 + rp) * 256 + xx) * 2];
            float gi = G[((b * 6 + rp) * 256 + xx) * 2 + 1];
            int u = (c * xx) & 255;
            Fr += gr * twl[u] - gi * twl[256 + u];
            Fi += gr * twl[256 + u] + gi * twl[u];
        }
    }
    fr[tid] = Fr; fi[tid] = Fi;
    __syncthreads();
    if (p < 30 && part == 0) {
        float sr = 0.f, si = 0.f;
        for (int k = 0; k < 8; k++) { sr += fr[p * 8 + k]; si += fi[p * 8 + k]; }
        float m = msg[b * 30 + p];
        dlt[b * 60 + p * 2]     = m - sr;
        dlt[b * 60 + p * 2 + 1] = m - si;
    }
}

// ---------------- final 1x1 conv, NHWC in, CHW fp32 out ----------------
__global__ void k_final(const u16* __restrict__ y5, const float* __restrict__ st,
                        const float* __restrict__ fw, const float* __restrict__ fb,
                        float* __restrict__ out) {
    __shared__ float fwl[192];
    __shared__ float sl[64], tl[64];
    __shared__ float fbl[3];
    int tid = threadIdx.x;
    if (tid < 192) fwl[tid] = fw[tid];
    if (tid < 64) { sl[tid] = st[tid * 2]; tl[tid] = st[tid * 2 + 1]; }
    if (tid < 3) fbl[tid] = fb[tid];
    __syncthreads();
    int e = blockIdx.x * 256 + tid;
    int b = e >> 16, px = e & 65535;
    float a0 = fbl[0], a1 = fbl[1], a2 = fbl[2];
    const u16* rowp = y5 + (size_t)e * 64;
    for (int cb = 0; cb < 8; cb++) {
        uint4 u = *reinterpret_cast<const uint4*>(rowp + cb * 8);
        unsigned wd[4] = {u.x, u.y, u.z, u.w};
#pragma unroll
        for (int q = 0; q < 4; q++) {
            int c = cb * 8 + 2 * q;
            float v0 = fmaxf(bfu2f(wd[q] & 0xffffu) * sl[c] + tl[c], 0.f);
            float v1 = fmaxf(bfu2f(wd[q] >> 16) * sl[c + 1] + tl[c + 1], 0.f);
            a0 += v0 * fwl[c] + v1 * fwl[c + 1];
            a1 += v0 * fwl[64 + c] + v1 * fwl[64 + c + 1];
            a2 += v0 * fwl[128 + c] + v1 * fwl[128 + c + 1];
        }
    }
    out[(b * 3 + 0) * NPX + px] = a0;
    out[(b * 3 + 1) * NPX + px] = a1;
    out[(b * 3 + 2) * NPX + px] = a2;
}

extern "C" void kernel_launch(void* const* d_in, const int* in_sizes, int n_in,
                              void* d_out, int out_size, void* d_ws, size_t ws_size,
                              hipStream_t stream) {
    (void)in_sizes; (void)n_in; (void)out_size; (void)ws_size;
    const float* image   = (const float*)d_in[0];
    const float* message = (const float*)d_in[1];
    const float* w0      = (const float*)d_in[2];
    const float* g0      = (const float*)d_in[4];
    const float* be0     = (const float*)d_in[5];
    const float* wsv     = (const float*)d_in[6];
    const float* gs      = (const float*)d_in[8];
    const float* bes     = (const float*)d_in[9];
    const float* acw     = (const float*)d_in[10];
    const float* acg     = (const float*)d_in[12];
    const float* acbe    = (const float*)d_in[13];
    const float* fw      = (const float*)d_in[14];
    const float* fb      = (const float*)d_in[15];
    float* out = (float*)d_out;

    // workspace layout — total 134,978,432 B (~128.7 MiB)
    u16* XA   = (u16*)d_ws;                // 33,554,432 u16 (64 MiB)
    u16* XB   = XA + 33554432;             // 33,554,432 u16 (64 MiB)
    // low-pass scratch ALIASES XB (dead before conv2 writes XB)
    float* Yb = (float*)XB;                // 1,241,088 f  [kxi][ch][y][2]
    float* Wb = Yb + 1241088;              // 1,241,088 f  [ch][y][kxi][2]
    float* LP = Wb + 1241088;              // 1,572,864 f
    u16* WPa  = XB + 33554432;             // 110,592 u16
    u16* WP5  = WPa + 110592;              // 55,296 u16
    float* TW   = (float*)(WP5 + 55296);   // 512 f
    float* D2T  = TW + 512;                // 25,856 f  [kxi][d]
    float* PART = D2T + 25856;             // 32,768 f
    float* ST   = PART + 32768;            // 128 f
    float* DLT  = ST + 128;                // 480 f
    float* G    = DLT + 480;               // 24,576 f
    float* WSm  = G + 24576;               // 17,280 f
    float* Mt   = WSm + 17280;             // 4,608 f
    double* TW64 = (double*)(Mt + 4608);   // 512 d (byte off 134,974,336 %8==0)

    dim3 cgrid(16, 16, 8);

    k_tables<<<103, 256, 0, stream>>>(TW, D2T, TW64);
    k_wprep<<<216, 64, 0, stream>>>(wsv, WPa);
    k_wprep5<<<108, 64, 0, stream>>>(acw, WP5);
    k_wsum<<<1, 256, 0, stream>>>(acw, WSm);
    k_msgM<<<8, 256, 0, stream>>>(message, WSm, Mt);

    k_lp1<<<dim3(64, 24), 256, 0, stream>>>(image, TW64, Yb);
    k_lp2<<<dim3(101, 6), 256, 0, stream>>>(Yb, D2T, Wb);
    k_lp3<<<dim3(256, 24), 256, 0, stream>>>(Wb, TW64, LP);

    // conv1 -> XA (raw NHWC bf16)
    k_conv1<<<cgrid, 256, 0, stream>>>(LP, w0, XA);
    k_stats<<<256, 256, 0, stream>>>(XA, PART);
    k_finalize<<<1, 256, 0, stream>>>(PART, g0, be0, ST);
    // conv2: XA -> XB (overwrites dead LP scratch)
    k_cmfma<0><<<cgrid, 256, 0, stream>>>(XA, WPa + 0 * 36864, ST, nullptr, nullptr, nullptr, nullptr, XB);
    k_stats<<<256, 256, 0, stream>>>(XB, PART);
    k_finalize<<<1, 256, 0, stream>>>(PART, gs + 0, bes + 0, ST);
    // conv3: XB -> XA
    k_cmfma<0><<<cgrid, 256, 0, stream>>>(XB, WPa + 1 * 36864, ST, nullptr, nullptr, nullptr, nullptr, XA);
    k_stats<<<256, 256, 0, stream>>>(XA, PART);
    k_finalize<<<1, 256, 0, stream>>>(PART, gs + 64, bes + 64, ST);
    // conv4: XA -> XB (raw y4)
    k_cmfma<0><<<cgrid, 256, 0, stream>>>(XA, WPa + 2 * 36864, ST, nullptr, nullptr, nullptr, nullptr, XB);
    k_stats<<<256, 256, 0, stream>>>(XB, PART);
    k_finalize<<<1, 256, 0, stream>>>(PART, gs + 128, bes + 128, ST);
    // watermark deltas from y4 ch0
    k_wmG<<<dim3(8, 8), 256, 0, stream>>>(XB, ST, TW, G);
    k_wmC<<<8, 256, 0, stream>>>(G, message, TW, DLT);
    // conv5 (enc staged from y4 + corr; img; msg via M term) -> XA
    k_cmfma<1><<<cgrid, 256, 0, stream>>>(XB, WP5, ST, image, DLT, TW, Mt, XA);
    k_stats<<<256, 256, 0, stream>>>(XA, PART);
    k_finalize<<<1, 256, 0, stream>>>(PART, acg, acbe, ST);
    // final 1x1 conv
    k_final<<<2048, 256, 0, stream>>>(XA, ST, fw, fb, out);
}

// Round 9
// 702.245 us; speedup vs baseline: 1.0714x; 1.0714x over previous
//
#include <hip/hip_runtime.h>
#include <math.h>

// ---------------------------------------------------------------------------
// Encoder_75557064671564 — MFMA bf16 conv stack, NHWC intermediates.
//
// ROUND-9:
//  - conv5 LDS 12kb -> 9kb: zero-pad blocks removed; icc=2 MFMA reads clamp
//    to kb8 (lanes with (l>>4)>=1 have zero A-weights -> any finite B ok).
//    51.8 KB -> 3 blocks/CU (was 67.6 KB -> 2, the round-8 regression).
//  - BN stats fused into conv epilogues (shfl reduce + LDS combine into the
//    dead twl buffer + atomicAdd into PART[64 slots][128]); k_stats deleted.
//    k_finalize sums slots and re-zeroes PART; one memset before conv1.
// lp chain: complex-rotation recurrence (round-7, verified).
// Workspace: 134,978,432 B (~128.7 MiB); LP scratch aliases XB.
// ---------------------------------------------------------------------------

#define NPX 65536
typedef unsigned short u16;
typedef __bf16 bfrag_t __attribute__((ext_vector_type(8)));
typedef float f32x4 __attribute__((ext_vector_type(4)));

__constant__ int WM_R_[30] = {124, 125,125,125,125,125, 126,126,126,126,126,126,126,
                              127,127,127,127,127,127,127,
                              128,128,128,128,128,128,128,128,128, 129};
__constant__ int WM_C_[30] = {128, 126,127,128,129,130, 125,126,127,128,129,130,131,
                              125,126,127,128,129,130,131,
                              124,125,126,127,128,129,130,131,132, 125};

__device__ __forceinline__ float bfu2f(unsigned int bits) {
    return __uint_as_float(bits << 16);
}
__device__ __forceinline__ u16 f2bu(float f) {
    unsigned int u = __float_as_uint(f);
    u += 0x7fffu + ((u >> 16) & 1u);
    return (u16)(u >> 16);
}
__device__ __forceinline__ unsigned cvt_pk(float lo, float hi) {
    unsigned r;
    asm("v_cvt_pk_bf16_f32 %0, %1, %2" : "=v"(r) : "v"(lo), "v"(hi));
    return r;
}

// ---------------- tables ----------------
__global__ void k_tables(float* __restrict__ tw, float* __restrict__ d2t,
                         double* __restrict__ twd64) {
    int idx = blockIdx.x * 256 + threadIdx.x;
    if (idx < 256) {
        double ang = -2.0 * M_PI * (double)idx / 256.0;
        tw[idx]       = (float)cos(ang);
        tw[256 + idx] = (float)sin(ang);
        twd64[idx]       = cos(ang);
        twd64[256 + idx] = sin(ang);
    }
    int q = idx - 256;
    if (q >= 0 && q < 256 * 101) {
        int d = q / 101, kxi = q - d * 101;
        int vx = (kxi <= 50) ? kxi : kxi - 101;
        int r2 = 2500 - vx * vx;
        int L = 0;
        while ((L + 1) * (L + 1) <= r2) L++;
        double s = 1.0;
        for (int v = 1; v <= L; v++) s += 2.0 * cos(2.0 * M_PI * (double)(v * d) / 256.0);
        d2t[kxi * 256 + d] = (float)(s / 256.0);
    }
}

// ---------------- low-pass chain (fp64, rotation recurrence) ----------------
__global__ __launch_bounds__(256) void k_lp1(const float* __restrict__ img,
        const double* __restrict__ twd64, float* __restrict__ Y) {
    __shared__ double rowd[4][256];
    int y0 = blockIdx.x * 4, ch = blockIdx.y, tid = threadIdx.x;
#pragma unroll
    for (int r = 0; r < 4; r++)
        rowd[r][tid] = (double)img[ch * NPX + (y0 + r) * 256 + tid];
    __syncthreads();
    int kxi = tid & 127, rg = tid >> 7;
    if (kxi >= 101) return;
    int kx = (kxi <= 50) ? kxi : kxi + 155;
    double cr = twd64[kx], ci = twd64[256 + kx];
    double wr = 1.0, wi = 0.0;
    double a0r = 0, a0i = 0, a1r = 0, a1i = 0;
    const double* r0 = rowd[2 * rg];
    const double* r1 = rowd[2 * rg + 1];
    for (int x = 0; x < 256; x++) {
        double v0 = r0[x], v1 = r1[x];
        a0r += v0 * wr; a0i += v0 * wi;
        a1r += v1 * wr; a1i += v1 * wi;
        double t = wr * cr - wi * ci;
        wi = wr * ci + wi * cr;
        wr = t;
    }
    int y = y0 + 2 * rg;
    int o = ((kxi * 24 + ch) * 256 + y) * 2;
    Y[o]     = (float)a0r; Y[o + 1] = (float)a0i;
    Y[o + 2] = (float)a1r; Y[o + 3] = (float)a1i;
}

__global__ __launch_bounds__(256) void k_lp2(const float* __restrict__ Y,
        const float* __restrict__ d2t, float* __restrict__ W) {
    __shared__ double Ys[4][256][2];
    __shared__ double Dc[256];
    int kxi = blockIdx.x, chg = blockIdx.y, tid = threadIdx.x;
    const float* src = Y + (size_t)(kxi * 24 + chg * 4) * 512;
    double* ysf = (double*)Ys;
    for (int i = tid; i < 2048; i += 256) ysf[i] = (double)src[i];
    Dc[tid] = (double)d2t[kxi * 256 + tid];
    __syncthreads();
    int cs = tid >> 6, y4 = tid & 63;
    double wr[4] = {0, 0, 0, 0}, wi[4] = {0, 0, 0, 0};
    for (int yp = 0; yp < 256; yp++) {
        double yr = Ys[cs][yp][0], yi = Ys[cs][yp][1];
        double D0 = Dc[(y4 - yp) & 255];
        double D1 = Dc[(y4 + 64 - yp) & 255];
        double D2 = Dc[(y4 + 128 - yp) & 255];
        double D3 = Dc[(y4 + 192 - yp) & 255];
        wr[0] += D0 * yr; wi[0] += D0 * yi;
        wr[1] += D1 * yr; wi[1] += D1 * yi;
        wr[2] += D2 * yr; wi[2] += D2 * yi;
        wr[3] += D3 * yr; wi[3] += D3 * yi;
    }
    int ch = chg * 4 + cs;
#pragma unroll
    for (int k = 0; k < 4; k++) {
        int y = y4 + 64 * k;
        int o = ((ch * 256 + y) * 101 + kxi) * 2;
        W[o] = (float)wr[k]; W[o + 1] = (float)wi[k];
    }
}

__global__ __launch_bounds__(256) void k_lp3(const float* __restrict__ W,
        const double* __restrict__ twd64, float* __restrict__ lp) {
    __shared__ double wsr[101], wsi[101];
    int y = blockIdx.x, ch = blockIdx.y, x = threadIdx.x;
    if (x < 101) {
        int kxi = (x < 50) ? (x + 51) : (x - 50);
        wsr[x] = (double)W[((ch * 256 + y) * 101 + kxi) * 2];
        wsi[x] = (double)W[((ch * 256 + y) * 101 + kxi) * 2 + 1];
    }
    __syncthreads();
    int t0 = (50 * x) & 255;
    double wr = twd64[t0], wi = -twd64[256 + t0];
    double cr = twd64[x], ci = twd64[256 + x];
    double acc = 0.0;
    for (int j = 0; j < 101; j++) {
        acc += wsr[j] * wr + wsi[j] * wi;
        double t = wr * cr - wi * ci;
        wi = wr * ci + wi * cr;
        wr = t;
    }
    acc *= (1.0 / 256.0);
    acc = floor(fmin(fmax(acc, 0.0), 255.0)) / 255.0;
    lp[ch * NPX + y * 256 + x] = (float)acc;
}

// ---------------- conv1: CIN=3, fp32 VALU, NHWC bf16 out + fused stats ------
__global__ __launch_bounds__(256, 2) void k_conv1(
    const float* __restrict__ lp, const float* __restrict__ w0,
    u16* __restrict__ out, float* __restrict__ part) {
    __shared__ float wl[3][9][64];
    __shared__ float al[3][18][18];
    int tid = threadIdx.x;
    int b = blockIdx.z, r0 = blockIdx.y * 16, c0 = blockIdx.x * 16;
    int ocg = tid >> 5, pxg = tid & 31;
    int row = pxg >> 1, chof = (pxg & 1) * 8;
    int oc0 = ocg * 8;
    float acc[8][8];
#pragma unroll
    for (int o = 0; o < 8; o++)
#pragma unroll
        for (int p = 0; p < 8; p++) acc[o][p] = 0.f;
    for (int idx = tid; idx < 1728; idx += 256) {
        int ic = idx / 576, rem = idx - ic * 576;
        int tap = rem >> 6, oc = rem & 63;
        wl[ic][tap][oc] = w0[(oc * 3 + ic) * 9 + tap];
    }
    for (int idx = tid; idx < 972; idx += 256) {
        int ic = idx / 324, rem = idx - ic * 324;
        int ly = rem / 18, lx = rem - ly * 18;
        int gy = r0 - 1 + ly, gx = c0 - 1 + lx;
        float v = 0.f;
        if ((unsigned)gy < 256u && (unsigned)gx < 256u)
            v = lp[(b * 3 + ic) * NPX + gy * 256 + gx];
        al[ic][ly][lx] = v;
    }
    __syncthreads();
    for (int ic = 0; ic < 3; ic++) {
        float areg[3][10];
#pragma unroll
        for (int di = 0; di < 3; di++)
#pragma unroll
            for (int xx = 0; xx < 10; xx++) areg[di][xx] = al[ic][row + di][chof + xx];
#pragma unroll
        for (int tap = 0; tap < 9; tap++) {
            const int di = tap / 3, dj = tap % 3;
            float wv[8];
#pragma unroll
            for (int o = 0; o < 8; o++) wv[o] = wl[ic][tap][oc0 + o];
#pragma unroll
            for (int o = 0; o < 8; o++)
#pragma unroll
                for (int p = 0; p < 8; p++)
                    acc[o][p] = fmaf(wv[o], areg[di][dj + p], acc[o][p]);
        }
    }
    float es1[8], es2[8];
#pragma unroll
    for (int o = 0; o < 8; o++) { es1[o] = 0.f; es2[o] = 0.f; }
#pragma unroll
    for (int p = 0; p < 8; p++) {
        unsigned wd[4];
#pragma unroll
        for (int q = 0; q < 4; q++)
            wd[q] = cvt_pk(acc[2 * q][p], acc[2 * q + 1][p]);
#pragma unroll
        for (int o = 0; o < 8; o++) {
            float v = acc[o][p];
            es1[o] += v; es2[o] += v * v;
        }
        size_t addr = ((size_t)((b * 256 + r0 + row) * 256 + c0 + chof + p)) * 64 + oc0;
        uint4 vv; vv.x = wd[0]; vv.y = wd[1]; vv.z = wd[2]; vv.w = wd[3];
        *reinterpret_cast<uint4*>(out + addr) = vv;
    }
    // reduce across the 32 threads sharing ocg (32-aligned lane group)
#pragma unroll
    for (int m = 1; m < 32; m <<= 1) {
#pragma unroll
        for (int o = 0; o < 8; o++) {
            es1[o] += __shfl_xor(es1[o], m);
            es2[o] += __shfl_xor(es2[o], m);
        }
    }
    if ((tid & 31) == 0) {
        int slot = (blockIdx.x + 16 * (blockIdx.y + 16 * blockIdx.z)) & 63;
        float* pp = part + slot * 128;
#pragma unroll
        for (int o = 0; o < 8; o++) {
            atomicAdd(&pp[(oc0 + o) * 2],     es1[o]);
            atomicAdd(&pp[(oc0 + o) * 2 + 1], es2[o]);
        }
    }
}

// ---------------- weight packing ----------------
__global__ void k_wprep(const float* __restrict__ wsv, u16* __restrict__ wp) {
    int bid = blockIdx.x;                  // 216 = 3 convs * 72
    int conv = bid / 72, fg = bid % 72;
    int icc = fg / 36, t2 = fg % 36, tap = t2 / 4, ocb = t2 % 4;
    int l = threadIdx.x;
    int oc = ocb * 16 + (l & 15);
    unsigned wd[4];
#pragma unroll
    for (int q = 0; q < 4; q++) {
        int ic0 = icc * 32 + (l >> 4) * 8 + 2 * q;
        float v0 = wsv[conv * 36864 + (oc * 64 + ic0) * 9 + tap];
        float v1 = wsv[conv * 36864 + (oc * 64 + ic0 + 1) * 9 + tap];
        wd[q] = (unsigned)f2bu(v0) | ((unsigned)f2bu(v1) << 16);
    }
    uint4 vv; vv.x = wd[0]; vv.y = wd[1]; vv.z = wd[2]; vv.w = wd[3];
    reinterpret_cast<uint4*>(wp)[conv * 4608 + fg * 64 + l] = vv;
}

__global__ void k_wprep5(const float* __restrict__ acw, u16* __restrict__ wp5) {
    int fg = blockIdx.x;                   // 108
    int icc = fg / 36, t2 = fg % 36, tap = t2 / 4, ocb = t2 % 4;
    int l = threadIdx.x;
    int oc = ocb * 16 + (l & 15);
    unsigned wd[4];
#pragma unroll
    for (int q = 0; q < 4; q++) {
        unsigned out2 = 0;
#pragma unroll
        for (int h = 0; h < 2; h++) {
            int icp = icc * 32 + (l >> 4) * 8 + 2 * q + h;
            float v = 0.f;
            if (icp < 67) v = acw[(oc * 97 + 30 + icp) * 9 + tap];
            out2 |= ((unsigned)f2bu(v)) << (16 * h);
        }
        wd[q] = out2;
    }
    uint4 vv; vv.x = wd[0]; vv.y = wd[1]; vv.z = wd[2]; vv.w = wd[3];
    reinterpret_cast<uint4*>(wp5)[fg * 64 + l] = vv;
}

__global__ void k_wsum(const float* __restrict__ acw, float* __restrict__ wsum) {
    for (int e = threadIdx.x; e < 17280; e += 256) {
        int oc = e / 270, r2 = e % 270, ic = r2 / 9, cls = r2 % 9;
        int cy = cls / 3, cx = cls % 3;
        int dil = (cy == 0) ? 1 : 0, dih = (cy == 2) ? 1 : 2;
        int djl = (cx == 0) ? 1 : 0, djh = (cx == 2) ? 1 : 2;
        float s = 0.f;
        for (int di = dil; di <= dih; di++)
            for (int dj = djl; dj <= djh; dj++)
                s += acw[(oc * 97 + ic) * 9 + di * 3 + dj];
        wsum[e] = s;
    }
}

__global__ void k_msgM(const float* __restrict__ msg, const float* __restrict__ wsum,
                       float* __restrict__ M) {
    int b = blockIdx.x;
    for (int t = threadIdx.x; t < 576; t += 256) {
        int oc = t / 9, cls = t % 9;
        float s = 0.f;
        for (int ic = 0; ic < 30; ic++)
            s += msg[b * 30 + ic] * wsum[oc * 270 + ic * 9 + cls];
        M[b * 576 + t] = s;
    }
}

// ---------------- MFMA conv3x3 (convs 2-5), v3 ----------------
// MODE 0: CIN=64 (8 kb). MODE 1: conv5, 9 kb (8 enc + 1 img); icc=2 reads
// clamp to kb8 (zero A-weights for (l>>4)>=1 make B values don't-care).
// BN stats fused: shfl reduce -> aux LDS (aliased with twl) -> atomicAdd.
template <int MODE>
__global__ __launch_bounds__(256, 3) void k_cmfma(
    const u16* __restrict__ src, const u16* __restrict__ wp,
    const float* __restrict__ st, const float* __restrict__ img,
    const float* __restrict__ dlt, const float* __restrict__ tw,
    const float* __restrict__ Mterm, u16* __restrict__ out,
    float* __restrict__ part) {
    const int NKB = (MODE == 0) ? 8 : 9;
    __shared__ __align__(16) u16 ain[NKB * 324 * 8];
    __shared__ float sst[128];
    __shared__ float aux[512];   // MODE1: twl during staging; sred in epilogue
    __shared__ float dl[(MODE == 1) ? 60 : 1];
    __shared__ float Ml[(MODE == 1) ? 576 : 1];

    int tid = threadIdx.x;
    int wv = tid >> 6, l = tid & 63;
    int b = blockIdx.z, y0 = blockIdx.y * 16, x0 = blockIdx.x * 16;

    if (tid < 128) sst[tid] = st[tid];
    if (MODE == 1) {
        aux[tid] = tw[tid]; aux[tid + 256] = tw[tid + 256];
        if (tid < 60) dl[tid] = dlt[b * 60 + tid];
        for (int i = tid; i < 576; i += 256) Ml[i] = Mterm[b * 576 + i];
    }
    __syncthreads();

    // ---- staging ----
    for (int px = tid; px < 324; px += 256) {
        int ly = px / 18, lx = px - ly * 18;
        int gy = y0 - 1 + ly, gx = x0 - 1 + lx;
        bool inb = ((unsigned)gy < 256u) && ((unsigned)gx < 256u);
        uint4* dst = reinterpret_cast<uint4*>(ain) + px;
        const uint4* gp = nullptr;
        if (inb) gp = reinterpret_cast<const uint4*>(
            src + ((size_t)((b * 256 + gy) * 256 + gx)) * 64);
        float corr = 0.f;
        if (MODE == 1 && inb) {
#pragma unroll
            for (int p = 0; p < 30; p++) {
                int t = (WM_R_[p] * gy + WM_C_[p] * gx) & 255;
                corr += dl[2 * p] * aux[t] + dl[2 * p + 1] * aux[256 + t];
            }
            corr *= (1.0f / 65536.0f);
        }
#pragma unroll
        for (int kb = 0; kb < 8; kb++) {
            uint4 pk; pk.x = 0; pk.y = 0; pk.z = 0; pk.w = 0;
            if (inb) {
                uint4 u = gp[kb];
                int cb = kb * 8;
                float f0 = fmaxf(bfu2f(u.x & 0xffffu) * sst[2 * cb + 0]  + sst[2 * cb + 1],  0.f);
                float f1 = fmaxf(bfu2f(u.x >> 16)     * sst[2 * cb + 2]  + sst[2 * cb + 3],  0.f);
                float f2 = fmaxf(bfu2f(u.y & 0xffffu) * sst[2 * cb + 4]  + sst[2 * cb + 5],  0.f);
                float f3 = fmaxf(bfu2f(u.y >> 16)     * sst[2 * cb + 6]  + sst[2 * cb + 7],  0.f);
                float f4 = fmaxf(bfu2f(u.z & 0xffffu) * sst[2 * cb + 8]  + sst[2 * cb + 9],  0.f);
                float f5 = fmaxf(bfu2f(u.z >> 16)     * sst[2 * cb + 10] + sst[2 * cb + 11], 0.f);
                float f6 = fmaxf(bfu2f(u.w & 0xffffu) * sst[2 * cb + 12] + sst[2 * cb + 13], 0.f);
                float f7 = fmaxf(bfu2f(u.w >> 16)     * sst[2 * cb + 14] + sst[2 * cb + 15], 0.f);
                if (MODE == 1 && kb == 0) f0 += corr;
                pk.x = cvt_pk(f0, f1); pk.y = cvt_pk(f2, f3);
                pk.z = cvt_pk(f4, f5); pk.w = cvt_pk(f6, f7);
            }
            dst[kb * 324] = pk;
        }
        if (MODE == 1) {
            uint4 p8; p8.x = 0; p8.y = 0; p8.z = 0; p8.w = 0;
            if (inb) {
                float v0 = img[(b * 3 + 0) * NPX + gy * 256 + gx];
                float v1 = img[(b * 3 + 1) * NPX + gy * 256 + gx];
                float v2 = img[(b * 3 + 2) * NPX + gy * 256 + gx];
                p8.x = cvt_pk(v0, v1);
                p8.y = cvt_pk(v2, 0.f);
            }
            dst[8 * 324] = p8;
        }
    }
    __syncthreads();

    // ---- MFMA phase ----
    f32x4 acc[4][4];
#pragma unroll
    for (int nt = 0; nt < 4; nt++)
#pragma unroll
        for (int ob = 0; ob < 4; ob++) acc[nt][ob] = (f32x4)(0.f);

    const uint4* wq = reinterpret_cast<const uint4*>(wp);
    const uint4* ap = reinterpret_cast<const uint4*>(ain);
    const int bl = (l >> 4) * 324 + (l & 15);
    const int wv4 = wv * 4;
    const int NIT = (MODE == 0) ? 18 : 27;

    uint4 a0 = wq[l], a1 = wq[64 + l], a2 = wq[128 + l], a3 = wq[192 + l];
#pragma unroll 1
    for (int it = 0; it < NIT; it++) {
        uint4 n0, n1, n2, n3;
        if (it + 1 < NIT) {
            const uint4* q = wq + (it + 1) * 256 + l;
            n0 = q[0]; n1 = q[64]; n2 = q[128]; n3 = q[192];
        }
        int icc = it / 9, tap = it - icc * 9;
        int di = tap / 3, dj = tap - di * 3;
        int abase = (MODE == 1 && icc == 2) ? (8 * 324 + (l & 15) + dj)
                                            : (icc * 4 * 324 + bl + dj);
#pragma unroll
        for (int nt = 0; nt < 4; nt++) {
            uint4 braw = ap[abase + (wv4 + nt + di) * 18];
            bfrag_t bf = __builtin_bit_cast(bfrag_t, braw);
            acc[nt][0] = __builtin_amdgcn_mfma_f32_16x16x32_bf16(
                __builtin_bit_cast(bfrag_t, a0), bf, acc[nt][0], 0, 0, 0);
            acc[nt][1] = __builtin_amdgcn_mfma_f32_16x16x32_bf16(
                __builtin_bit_cast(bfrag_t, a1), bf, acc[nt][1], 0, 0, 0);
            acc[nt][2] = __builtin_amdgcn_mfma_f32_16x16x32_bf16(
                __builtin_bit_cast(bfrag_t, a2), bf, acc[nt][2], 0, 0, 0);
            acc[nt][3] = __builtin_amdgcn_mfma_f32_16x16x32_bf16(
                __builtin_bit_cast(bfrag_t, a3), bf, acc[nt][3], 0, 0, 0);
        }
        a0 = n0; a1 = n1; a2 = n2; a3 = n3;
    }

    // ---- epilogue + fused stats ----
    int x = x0 + (l & 15);
    int ocq = (l >> 4) * 4;
    int clsx = (x == 0) ? 0 : ((x == 255) ? 2 : 1);
    float es1[16], es2[16];
#pragma unroll
    for (int k = 0; k < 16; k++) { es1[k] = 0.f; es2[k] = 0.f; }
#pragma unroll
    for (int nt = 0; nt < 4; nt++) {
        int y = y0 + wv4 + nt;
#pragma unroll
        for (int ob = 0; ob < 4; ob++) {
            int oc = ob * 16 + ocq;
            float v0 = acc[nt][ob][0], v1 = acc[nt][ob][1];
            float v2 = acc[nt][ob][2], v3 = acc[nt][ob][3];
            if (MODE == 1) {
                int cls = ((y == 0) ? 0 : ((y == 255) ? 6 : 3)) + clsx;
                v0 += Ml[(oc + 0) * 9 + cls];
                v1 += Ml[(oc + 1) * 9 + cls];
                v2 += Ml[(oc + 2) * 9 + cls];
                v3 += Ml[(oc + 3) * 9 + cls];
            }
            es1[ob * 4 + 0] += v0; es2[ob * 4 + 0] += v0 * v0;
            es1[ob * 4 + 1] += v1; es2[ob * 4 + 1] += v1 * v1;
            es1[ob * 4 + 2] += v2; es2[ob * 4 + 2] += v2 * v2;
            es1[ob * 4 + 3] += v3; es2[ob * 4 + 3] += v3 * v3;
            uint2 pk;
            pk.x = cvt_pk(v0, v1);
            pk.y = cvt_pk(v2, v3);
            size_t addr = ((size_t)((b * 256 + y) * 256 + x)) * 64 + oc;
            *reinterpret_cast<uint2*>(out + addr) = pk;
        }
    }
    // 16-lane reduce (lanes sharing l>>4)
#pragma unroll
    for (int m = 1; m < 16; m <<= 1) {
#pragma unroll
        for (int k = 0; k < 16; k++) {
            es1[k] += __shfl_xor(es1[k], m);
            es2[k] += __shfl_xor(es2[k], m);
        }
    }
    __syncthreads();               // staging reads of aux are long done
    if ((l & 15) == 0) {
#pragma unroll
        for (int k = 0; k < 16; k++) {
            int ob = k >> 2, q = k & 3;
            int oc = ob * 16 + ocq + q;
            aux[wv * 128 + oc * 2]     = es1[k];
            aux[wv * 128 + oc * 2 + 1] = es2[k];
        }
    }
    __syncthreads();
    if (tid < 128) {
        float v = aux[tid] + aux[128 + tid] + aux[256 + tid] + aux[384 + tid];
        int slot = (blockIdx.x + 16 * (blockIdx.y + 16 * blockIdx.z)) & 63;
        atomicAdd(&part[slot * 128 + tid], v);
    }
}

// ---------------- finalize: PART[64][128] -> st; re-zero PART ----------------
__global__ void k_finalize(float* __restrict__ part, const float* __restrict__ g,
                           const float* __restrict__ be, float* __restrict__ st) {
    int c = threadIdx.x;   // 64 threads
    double S1 = 0.0, S2 = 0.0;
    for (int k = 0; k < 64; k++) {
        S1 += (double)part[k * 128 + c * 2];
        S2 += (double)part[k * 128 + c * 2 + 1];
    }
    const double Nn = 524288.0;
    double mean = S1 / Nn;
    double var = S2 / Nn - mean * mean;
    float s = (float)((double)g[c] / sqrt(var + 1e-5));
    float t = (float)((double)be[c] - mean * (double)s);
    __syncthreads();
    for (int k = c; k < 8192; k += 64) part[k] = 0.f;
    st[c * 2] = s; st[c * 2 + 1] = t;
}

// ---------------- watermark coefficient passes ----------------
__global__ void k_wmG(const u16* __restrict__ y4, const float* __restrict__ st,
                      const float* __restrict__ tw, float* __restrict__ G) {
    __shared__ float twl[512];
    __shared__ float red[256][12];
    int b = blockIdx.x, xg = blockIdx.y, tid = threadIdx.x;
    twl[tid] = tw[tid]; twl[tid + 256] = tw[tid + 256];
    __syncthreads();
    int xs = tid & 31, x = xg * 32 + xs, yg = tid >> 5;
    float s0 = st[0], t0 = st[1];
    float gr[6], gi[6];
#pragma unroll
    for (int r = 0; r < 6; r++) { gr[r] = 0.f; gi[r] = 0.f; }
    for (int yy = 0; yy < 32; yy++) {
        int y = yg * 32 + yy;
        float v = fmaxf(bfu2f((unsigned)y4[((size_t)((b * 256 + y) * 256 + x)) * 64]) * s0 + t0, 0.f);
#pragma unroll
        for (int r = 0; r < 6; r++) {
            int t = ((124 + r) * y) & 255;
            gr[r] += v * twl[t];
            gi[r] += v * twl[256 + t];
        }
    }
#pragma unroll
    for (int r = 0; r < 6; r++) { red[tid][2 * r] = gr[r]; red[tid][2 * r + 1] = gi[r]; }
    __syncthreads();
    for (int e = tid; e < 384; e += 256) {
        int xs2 = e & 31, c = e >> 5;
        float s = 0.f;
        for (int g = 0; g < 8; g++) s += red[g * 32 + xs2][c];
        int r = c >> 1, ri = c & 1;
        G[((b * 6 + r) * 256 + (xg * 32 + xs2)) * 2 + ri] = s;
    }
}

__global__ void k_wmC(const float* __restrict__ G, const float* __restrict__ msg,
                      const float* __restrict__ tw, float* __restrict__ dlt) {
    __shared__ float twl[512];
    __shared__ float fr[256], fi[256];
    int b = blockIdx.x, tid = threadIdx.x;
    twl[tid] = tw[tid]; twl[tid + 256] = tw[tid + 256];
    __syncthreads();
    int p = tid >> 3, part = tid & 7;
    float Fr = 0.f, Fi = 0.f;
    if (p < 30) {
        int rp = WM_R_[p] - 124, c = WM_C_[p];
        for (int xx = part * 32; xx < part * 32 + 32; xx++) {
            float gr = G[((b * 6 + rp) * 256 + xx) * 2];
            float gi = G[((b * 6 + rp) * 256 + xx) * 2 + 1];
            int u = (c * xx) & 255;
            Fr += gr * twl[u] - gi * twl[256 + u];
            Fi += gr * twl[256 + u] + gi * twl[u];
        }
    }
    fr[tid] = Fr; fi[tid] = Fi;
    __syncthreads();
    if (p < 30 && part == 0) {
        float sr = 0.f, si = 0.f;
        for (int k = 0; k < 8; k++) { sr += fr[p * 8 + k]; si += fi[p * 8 + k]; }
        float m = msg[b * 30 + p];
        dlt[b * 60 + p * 2]     = m - sr;
        dlt[b * 60 + p * 2 + 1] = m - si;
    }
}

// ---------------- final 1x1 conv, NHWC in, CHW fp32 out ----------------
__global__ void k_final(const u16* __restrict__ y5, const float* __restrict__ st,
                        const float* __restrict__ fw, const float* __restrict__ fb,
                        float* __restrict__ out) {
    __shared__ float fwl[192];
    __shared__ float sl[64], tl[64];
    __shared__ float fbl[3];
    int tid = threadIdx.x;
    if (tid < 192) fwl[tid] = fw[tid];
    if (tid < 64) { sl[tid] = st[tid * 2]; tl[tid] = st[tid * 2 + 1]; }
    if (tid < 3) fbl[tid] = fb[tid];
    __syncthreads();
    int e = blockIdx.x * 256 + tid;
    int b = e >> 16, px = e & 65535;
    float a0 = fbl[0], a1 = fbl[1], a2 = fbl[2];
    const u16* rowp = y5 + (size_t)e * 64;
    for (int cb = 0; cb < 8; cb++) {
        uint4 u = *reinterpret_cast<const uint4*>(rowp + cb * 8);
        unsigned wd[4] = {u.x, u.y, u.z, u.w};
#pragma unroll
        for (int q = 0; q < 4; q++) {
            int c = cb * 8 + 2 * q;
            float v0 = fmaxf(bfu2f(wd[q] & 0xffffu) * sl[c] + tl[c], 0.f);
            float v1 = fmaxf(bfu2f(wd[q] >> 16) * sl[c + 1] + tl[c + 1], 0.f);
            a0 += v0 * fwl[c] + v1 * fwl[c + 1];
            a1 += v0 * fwl[64 + c] + v1 * fwl[64 + c + 1];
            a2 += v0 * fwl[128 + c] + v1 * fwl[128 + c + 1];
        }
    }
    out[(b * 3 + 0) * NPX + px] = a0;
    out[(b * 3 + 1) * NPX + px] = a1;
    out[(b * 3 + 2) * NPX + px] = a2;
}

extern "C" void kernel_launch(void* const* d_in, const int* in_sizes, int n_in,
                              void* d_out, int out_size, void* d_ws, size_t ws_size,
                              hipStream_t stream) {
    (void)in_sizes; (void)n_in; (void)out_size; (void)ws_size;
    const float* image   = (const float*)d_in[0];
    const float* message = (const float*)d_in[1];
    const float* w0      = (const float*)d_in[2];
    const float* g0      = (const float*)d_in[4];
    const float* be0     = (const float*)d_in[5];
    const float* wsv     = (const float*)d_in[6];
    const float* gs      = (const float*)d_in[8];
    const float* bes     = (const float*)d_in[9];
    const float* acw     = (const float*)d_in[10];
    const float* acg     = (const float*)d_in[12];
    const float* acbe    = (const float*)d_in[13];
    const float* fw      = (const float*)d_in[14];
    const float* fb      = (const float*)d_in[15];
    float* out = (float*)d_out;

    // workspace layout — total 134,978,432 B (~128.7 MiB)
    u16* XA   = (u16*)d_ws;                // 33,554,432 u16 (64 MiB)
    u16* XB   = XA + 33554432;             // 33,554,432 u16 (64 MiB)
    float* Yb = (float*)XB;                // lp scratch aliases XB
    float* Wb = Yb + 1241088;
    float* LP = Wb + 1241088;
    u16* WPa  = XB + 33554432;             // 110,592 u16
    u16* WP5  = WPa + 110592;              // 55,296 u16
    float* TW   = (float*)(WP5 + 55296);   // 512 f
    float* D2T  = TW + 512;                // 25,856 f
    float* PART = D2T + 25856;             // 8,192 f (64 slots x 128)
    float* ST   = PART + 32768;            // 128 f (PART region kept 32768 for layout compat)
    float* DLT  = ST + 128;                // 480 f
    float* G    = DLT + 480;               // 24,576 f
    float* WSm  = G + 24576;               // 17,280 f
    float* Mt   = WSm + 17280;             // 4,608 f
    double* TW64 = (double*)(Mt + 4608);   // 512 d

    dim3 cgrid(16, 16, 8);

    hipMemsetAsync(PART, 0, 32768, stream);
    k_tables<<<103, 256, 0, stream>>>(TW, D2T, TW64);
    k_wprep<<<216, 64, 0, stream>>>(wsv, WPa);
    k_wprep5<<<108, 64, 0, stream>>>(acw, WP5);
    k_wsum<<<1, 256, 0, stream>>>(acw, WSm);
    k_msgM<<<8, 256, 0, stream>>>(message, WSm, Mt);

    k_lp1<<<dim3(64, 24), 256, 0, stream>>>(image, TW64, Yb);
    k_lp2<<<dim3(101, 6), 256, 0, stream>>>(Yb, D2T, Wb);
    k_lp3<<<dim3(256, 24), 256, 0, stream>>>(Wb, TW64, LP);

    // conv1 -> XA (raw NHWC bf16) + fused stats
    k_conv1<<<cgrid, 256, 0, stream>>>(LP, w0, XA, PART);
    k_finalize<<<1, 64, 0, stream>>>(PART, g0, be0, ST);
    // conv2: XA -> XB
    k_cmfma<0><<<cgrid, 256, 0, stream>>>(XA, WPa + 0 * 36864, ST, nullptr, nullptr, nullptr, nullptr, XB, PART);
    k_finalize<<<1, 64, 0, stream>>>(PART, gs + 0, bes + 0, ST);
    // conv3: XB -> XA
    k_cmfma<0><<<cgrid, 256, 0, stream>>>(XB, WPa + 1 * 36864, ST, nullptr, nullptr, nullptr, nullptr, XA, PART);
    k_finalize<<<1, 64, 0, stream>>>(PART, gs + 64, bes + 64, ST);
    // conv4: XA -> XB (raw y4)
    k_cmfma<0><<<cgrid, 256, 0, stream>>>(XA, WPa + 2 * 36864, ST, nullptr, nullptr, nullptr, nullptr, XB, PART);
    k_finalize<<<1, 64, 0, stream>>>(PART, gs + 128, bes + 128, ST);
    // watermark deltas from y4 ch0
    k_wmG<<<dim3(8, 8), 256, 0, stream>>>(XB, ST, TW, G);
    k_wmC<<<8, 256, 0, stream>>>(G, message, TW, DLT);
    // conv5 -> XA
    k_cmfma<1><<<cgrid, 256, 0, stream>>>(XB, WP5, ST, image, DLT, TW, Mt, XA, PART);
    k_finalize<<<1, 64, 0, stream>>>(PART, acg, acbe, ST);
    // final 1x1 conv
    k_final<<<2048, 256, 0, stream>>>(XA, ST, fw, fb, out);
}